// Round 1
// baseline (302.688 us; speedup 1.0000x reference)
//
#include <hip/hip_runtime.h>
#include <cstdint>
#include <cstddef>

// Attention: B=4, S=2048, H=1024 (single "head", d=1024). fp32 I/O buffers.
// Pipeline: cvt x,W* to bf16 ; fused QKV GEMM (N=3072 -> Q,K,Vt) ;
//           Sc = Q·Kᵀ/32 (fp16) ; P = softmax(Sc) (bf16) ; out = P·Vtᵀ (fp32).
//
// R10: replace the 128²/2-barrier gemm_bt (719 TF, MfmaUtil 29%) with a
// 256²/BK=32 multi-phase counted-vmcnt schedule (T2+T3+T4+T5):
//   - 8 waves (512 thr), wave grid 2M x 4N, per-wave 128x64 out (acc[8][4]).
//   - 4 LDS buffers x (16KB A + 16KB B) = 128KB dynamic LDS, 1 block/CU.
//   - 2 phases per K-tile: phase0 = Mfrags0-3 x Nfrags0-3 (8 ds_read_b128),
//     phase1 = Mfrags4-7 (4 ds_read, B-frags reused in regs); 16 MFMA each.
//   - each phase stages ONE operand-unit (16KB, 2 global_load_lds/thread)
//     3 K-tiles ahead.  Schedule proof:
//       * overwrite-safe: unit of tile t+3 lands in buf (t+3)&3 = (t-1)&3,
//         whose last reads ended before the barrier closing tile t-1; the
//         stage is issued after that barrier, and DMA can't write pre-issue.
//       * read-safe: vmcnt(8) fused with the K-tile-boundary s_barrier in one
//         opaque asm (memory clobber: next tile's ds_reads can't hoist).
//         8 outstanding = the 4 newest units (tiles t+2,t+3) => tile t+1 landed.
//     Tail: vmcnt(4) at t==NT-3, vmcnt(0) at t==NT-2, none at NT-1.
//   - LDS layout pair-interleaves rows: line = row>>1,
//     slot = ((chunk<<1)|(row&1)) ^ (line&7).  A wave's ds_read_b128 puts
//     exactly 8 lanes on each 128B line covering all 8 16B slots -> conflict-
//     free.  Staged via inverse-permuted GLOBAL source + linear LDS dest.
//
// ws layout (102 MB): [0,16M) xb ; [16,22M) Wqkv bf16 (Wq|Wk|Wv) ;
//   [22,38M) Q ; [38,54M) Kp ; [54,70M) Vt ; [70,102M) Sc fp16 ;
//   P overlays [22,54M) (Q|Kp dead after scores GEMM).

typedef __bf16 bf16;
typedef _Float16 f16;
typedef __bf16 bf16x8 __attribute__((ext_vector_type(8)));
typedef __bf16 bf16x4 __attribute__((ext_vector_type(4)));
typedef _Float16 f16x8 __attribute__((ext_vector_type(8)));
typedef float f32x4 __attribute__((ext_vector_type(4)));

#define BM 256
#define BN 256
#define BK 32
#define UNIT_BYTES 16384   // one operand K-tile: 256 rows x 32 cols x 2B
#define BBASE 65536        // B units start at 64KB; total LDS = 128KB
#define LDS_TOTAL 131072

// Fused fp32->bf16 convert: x (XQ quads) -> xb, then Wq|Wk|Wv (WQ quads each)
// -> contiguous Wqkv. One dispatch.
#define XQ (8388608 / 4)
#define WQ (1048576 / 4)
__global__ __launch_bounds__(256)
void cvt_all(const float* __restrict__ x, const float* __restrict__ Wq,
             const float* __restrict__ Wk, const float* __restrict__ Wv,
             bf16* __restrict__ xb, bf16* __restrict__ Wqkv)
{
    const int i = blockIdx.x * 256 + threadIdx.x;
    const float* src;
    bf16* dst;
    if (i < XQ) {
        src = x + 4 * (size_t)i;
        dst = xb + 4 * (size_t)i;
    } else {
        const int j = i - XQ;                 // 0 .. 3*WQ-1
        const int w = j / WQ;                 // 0..2
        const int off = j - w * WQ;
        const float* ws_ = (w == 0) ? Wq : (w == 1) ? Wk : Wv;
        src = ws_ + 4 * (size_t)off;
        dst = Wqkv + 4 * (size_t)j;
    }
    f32x4 v = *(const f32x4*)src;
    bf16x4 o;
#pragma unroll
    for (int r = 0; r < 4; ++r) o[r] = (bf16)v[r];
    *(bf16x4*)dst = o;
}

// byte offset of fragment (row, chunk) within one 16KB unit
__device__ __forceinline__ int frag_off(int row, int chunk)
{
    const int line = row >> 1;
    const int pos = ((chunk << 1) | (row & 1)) ^ (line & 7);
    return line * 128 + pos * 16;
}

// OUTMODE: 2 = f16 out, scaled by alpha (scores)
//          3 = f32 out (final O -> d_out)
//          4 = fused QKV: col3>>10 selects {Q,K,Vt}; bias0/1/2 = bq/bk/bv.
template <int OUTMODE>
__global__ __launch_bounds__(512, 2)
void gemm256(const bf16* __restrict__ A, const bf16* __restrict__ Bm,
             const float* __restrict__ bias0, const float* __restrict__ bias1,
             const float* __restrict__ bias2, void* __restrict__ C,
             int K, int N, float alpha, long zA, long zB, long zC)
{
    extern __shared__ __align__(16) bf16 smem[];
    auto lds3 = (__attribute__((address_space(3))) char*)smem;

    const int tid  = threadIdx.x;
    const int lane = tid & 63;
    const int wid  = tid >> 6;
    const int quad = lane >> 4;
    const int l16  = lane & 15;
    const int wr   = (wid >> 2) * 128;   // wave row offset in 256 tile
    const int wc   = (wid & 3) * 64;     // wave col offset in 256 tile

    const int m0 = blockIdx.y * BM;
    const int n0 = blockIdx.x * BN;
    const int z  = blockIdx.z;

    const bf16* Ab = A + (size_t)z * zA + (size_t)m0 * K;
    const bf16* Bb = Bm + (size_t)z * zB + (size_t)n0 * K;

    // per-thread DMA global-source offsets (elements) for issue 0/1.
    // DMA writes linear slots s = issue*512 + tid; invert the LDS permutation
    // so slot s receives the (row, chunk) that the swizzled reader expects.
    int soff0, soff1;
    {
        const int s0 = tid, s1 = 512 + tid;
        int line = s0 >> 3, un = (s0 & 7) ^ (line & 7);
        soff0 = ((line << 1) | (un & 1)) * K + (un >> 1) * 8;
        line = s1 >> 3; un = (s1 & 7) ^ (line & 7);
        soff1 = ((line << 1) | (un & 1)) * K + (un >> 1) * 8;
    }
    const unsigned wb0 = (unsigned)(wid * 1024);

#define STAGE(gsrc, ldsbase)                                                   \
    do {                                                                       \
        __builtin_amdgcn_global_load_lds(                                      \
            (const __attribute__((address_space(1))) void*)((gsrc) + soff0),   \
            (__attribute__((address_space(3))) void*)(lds3 + (ldsbase) + wb0), \
            16, 0, 0);                                                         \
        __builtin_amdgcn_global_load_lds(                                      \
            (const __attribute__((address_space(1))) void*)((gsrc) + soff1),   \
            (__attribute__((address_space(3))) void*)(lds3 + (ldsbase) + 8192 + wb0), \
            16, 0, 0);                                                         \
    } while (0)

    // per-thread fragment byte offsets within a unit (loop-invariant)
    int aoff[8], boff[4];
#pragma unroll
    for (int i = 0; i < 8; ++i) aoff[i] = frag_off(wr + i * 16 + l16, quad);
#pragma unroll
    for (int j = 0; j < 4; ++j) boff[j] = frag_off(wc + j * 16 + l16, quad);

    const int NT = K / BK;
    f32x4 acc[8][4] = {};

    // prologue: stage tiles 0..2 (A and B each), then wait tile 0 landed
    // (12 loads issued; vmcnt(8) => units 0,1 = tile 0 A+B landed)
#pragma unroll
    for (int tt = 0; tt < 3; ++tt) {
        STAGE(Ab + tt * BK, (unsigned)(tt * UNIT_BYTES));
        STAGE(Bb + tt * BK, (unsigned)(BBASE + tt * UNIT_BYTES));
    }
    asm volatile("s_waitcnt vmcnt(8)\n\ts_barrier" ::: "memory");

#pragma unroll 4
    for (int t = 0; t < NT; ++t) {
        const char* Au = (const char*)smem + (t & 3) * UNIT_BYTES;
        const char* Bu = (const char*)smem + BBASE + (t & 3) * UNIT_BYTES;
        bf16x8 af[4], bfr[4];

        // ---- phase 0: Mfrags 0-3 x Nfrags 0-3 ----
#pragma unroll
        for (int i = 0; i < 4; ++i) af[i] = *(const bf16x8*)(Au + aoff[i]);
#pragma unroll
        for (int j = 0; j < 4; ++j) bfr[j] = *(const bf16x8*)(Bu + boff[j]);
        if (t < NT - 3)
            STAGE(Ab + (t + 3) * BK, (unsigned)(((t + 3) & 3) * UNIT_BYTES));
        asm volatile("s_barrier\n\ts_waitcnt lgkmcnt(0)" ::: "memory");
        __builtin_amdgcn_s_setprio(1);
#pragma unroll
        for (int i = 0; i < 4; ++i)
#pragma unroll
            for (int j = 0; j < 4; ++j)
                acc[i][j] = __builtin_amdgcn_mfma_f32_16x16x32_bf16(
                    af[i], bfr[j], acc[i][j], 0, 0, 0);
        __builtin_amdgcn_s_setprio(0);
        asm volatile("s_barrier" ::: "memory");

        // ---- phase 1: Mfrags 4-7 x Nfrags 0-3 (bfr reused in regs) ----
#pragma unroll
        for (int i = 0; i < 4; ++i) af[i] = *(const bf16x8*)(Au + aoff[4 + i]);
        if (t < NT - 3)
            STAGE(Bb + (t + 3) * BK, (unsigned)(BBASE + ((t + 3) & 3) * UNIT_BYTES));
        asm volatile("s_barrier\n\ts_waitcnt lgkmcnt(0)" ::: "memory");
        __builtin_amdgcn_s_setprio(1);
#pragma unroll
        for (int i = 0; i < 4; ++i)
#pragma unroll
            for (int j = 0; j < 4; ++j)
                acc[4 + i][j] = __builtin_amdgcn_mfma_f32_16x16x32_bf16(
                    af[i], bfr[j], acc[4 + i][j], 0, 0, 0);
        __builtin_amdgcn_s_setprio(0);
        // K-tile boundary: counted landing guarantee fused with the barrier
        if (t < NT - 3)
            asm volatile("s_waitcnt vmcnt(8)\n\ts_barrier" ::: "memory");
        else if (t == NT - 3)
            asm volatile("s_waitcnt vmcnt(4)\n\ts_barrier" ::: "memory");
        else if (t == NT - 2)
            asm volatile("s_waitcnt vmcnt(0)\n\ts_barrier" ::: "memory");
        else
            asm volatile("s_barrier" ::: "memory");
    }
#undef STAGE

    // Epilogue. C/D layout (verified m89): col = lane&15, row = quad*4 + reg.
#pragma unroll
    for (int j = 0; j < 4; ++j) {
        const int col3 = n0 + wc + j * 16 + l16;
#pragma unroll
        for (int i = 0; i < 8; ++i) {
            const int rbase = m0 + wr + i * 16 + quad * 4;
            if (OUTMODE == 2) {
                f16* Cf = (f16*)C + (size_t)z * zC;
#pragma unroll
                for (int r = 0; r < 4; ++r)
                    Cf[(size_t)(rbase + r) * N + col3] = (f16)(acc[i][j][r] * alpha);
            } else if (OUTMODE == 3) {
                float* Cf = (float*)C + (size_t)z * zC;
#pragma unroll
                for (int r = 0; r < 4; ++r)
                    Cf[(size_t)(rbase + r) * N + col3] = acc[i][j][r];
            } else { // OUTMODE == 4
                const int mat = col3 >> 10;           // 0=Q 1=K 2=V
                const int col = col3 & 1023;
                const float* bp = (mat == 0) ? bias0 : (mat == 1) ? bias1 : bias2;
                const float bj = bp[col];
                if (mat < 2) {
                    bf16* Cb = (bf16*)C + (size_t)mat * (8u << 20);
#pragma unroll
                    for (int r = 0; r < 4; ++r)
                        Cb[(size_t)(rbase + r) * 1024 + col] =
                            (bf16)(acc[i][j][r] + bj);
                } else {
                    // Vt[b][col][s] = V[b*2048+s][col]; quad rows are 4
                    // consecutive s -> one 8B same-type vector store.
                    bf16* Cb = (bf16*)C + (size_t)(16u << 20);
                    const int b = rbase >> 11;
                    const int s = rbase & 2047;
                    bf16x4 tmp;
#pragma unroll
                    for (int r = 0; r < 4; ++r) tmp[r] = (bf16)(acc[i][j][r] + bj);
                    *(bf16x4*)(Cb + (((size_t)((b << 10) + col)) << 11) + s) = tmp;
                }
            }
        }
    }
}

__device__ __forceinline__ float wred_max(float v)
{
#pragma unroll
    for (int o = 32; o > 0; o >>= 1) v = fmaxf(v, __shfl_xor(v, o, 64));
    return v;
}
__device__ __forceinline__ float wred_sum(float v)
{
#pragma unroll
    for (int o = 32; o > 0; o >>= 1) v += __shfl_xor(v, o, 64);
    return v;
}

__global__ __launch_bounds__(256)
void softmax_rows(const f16* __restrict__ Sc, bf16* __restrict__ P)
{
    constexpr int NC = 2048;
    const size_t row = blockIdx.x;
    const f16* src = Sc + row * NC;
    bf16* dst = P + row * NC;
    const int tid = threadIdx.x;

    // vectorized 16B loads: each thread owns 8 contiguous elements
    f16x8 in = *(const f16x8*)(src + tid * 8);
    float v[8];
    float m = -3.4e38f;
#pragma unroll
    for (int i = 0; i < 8; ++i) {
        v[i] = (float)in[i];
        m = fmaxf(m, v[i]);
    }
    m = wred_max(m);

    __shared__ float redm[4], reds[4];
    if ((tid & 63) == 0) redm[tid >> 6] = m;
    __syncthreads();
    m = fmaxf(fmaxf(redm[0], redm[1]), fmaxf(redm[2], redm[3]));

    float s = 0.f;
#pragma unroll
    for (int i = 0; i < 8; ++i) { v[i] = __expf(v[i] - m); s += v[i]; }
    s = wred_sum(s);
    if ((tid & 63) == 0) reds[tid >> 6] = s;
    __syncthreads();
    s = reds[0] + reds[1] + reds[2] + reds[3];

    const float inv = 1.f / s;
    bf16x8 o;
#pragma unroll
    for (int i = 0; i < 8; ++i) o[i] = (bf16)(v[i] * inv);
    *(bf16x8*)(dst + tid * 8) = o;
}

extern "C" void kernel_launch(void* const* d_in, const int* in_sizes, int n_in,
                              void* d_out, int out_size, void* d_ws, size_t ws_size,
                              hipStream_t stream)
{
    constexpr int B = 4, S = 2048, H = 1024;
    const float* x  = (const float*)d_in[0];
    const float* Wq = (const float*)d_in[1];
    const float* bq = (const float*)d_in[2];
    const float* Wk = (const float*)d_in[3];
    const float* bk = (const float*)d_in[4];
    const float* Wv = (const float*)d_in[5];
    const float* bv = (const float*)d_in[6];
    float* out = (float*)d_out;

    char* ws = (char*)d_ws;
    bf16* xb   = (bf16*)ws;                         // 16 MB
    bf16* Wqkv = (bf16*)(ws + (size_t)(16 << 20));  //  6 MB (Wq|Wk|Wv bf16)
    bf16* Q    = (bf16*)(ws + (size_t)(22 << 20));  // 16 MB
    bf16* Kp   = (bf16*)(ws + (size_t)(38 << 20));  // 16 MB
    bf16* Vt   = (bf16*)(ws + (size_t)(54 << 20));  // 16 MB
    f16*  Sc   = (f16*) (ws + (size_t)(70 << 20));  // 32 MB (fp16 scores)
    bf16* P    = (bf16*)(ws + (size_t)(22 << 20));  // 32 MB, overlays Q|Kp

    // raise dynamic-LDS cap to 128KB once (host-side attr; not a stream op)
    static bool attr_done = false;
    if (!attr_done) {
        attr_done = true;
        (void)hipFuncSetAttribute(reinterpret_cast<const void*>(gemm256<4>),
                                  hipFuncAttributeMaxDynamicSharedMemorySize,
                                  LDS_TOTAL);
        (void)hipFuncSetAttribute(reinterpret_cast<const void*>(gemm256<2>),
                                  hipFuncAttributeMaxDynamicSharedMemorySize,
                                  LDS_TOTAL);
        (void)hipFuncSetAttribute(reinterpret_cast<const void*>(gemm256<3>),
                                  hipFuncAttributeMaxDynamicSharedMemorySize,
                                  LDS_TOTAL);
    }

    dim3 blk(256, 1, 1);
    dim3 blk512(512, 1, 1);

    // fp32 -> bf16 conversions, one dispatch (x -> xb, Wq|Wk|Wv -> Wqkv)
    cvt_all<<<dim3((XQ + 3 * WQ) / 256), blk, 0, stream>>>(
        x, Wq, Wk, Wv, xb, Wqkv);

    // Fused QKV projection: M = 8192, N = 3072, K = 1024 -> Q, Kp, Vt
    gemm256<4><<<dim3(3 * H / BN, (B * S) / BM, 1), blk512, LDS_TOTAL, stream>>>(
        xb, Wqkv, bq, bk, bv, Q, H, 3 * H, 1.0f, 0, 0, 0);

    // Scores: per batch (grid.z), Sc = Q·Kᵀ / 32, fp16
    gemm256<2><<<dim3(S / BN, S / BM, B), blk512, LDS_TOTAL, stream>>>(
        Q, Kp, nullptr, nullptr, nullptr, Sc, H, S, 0.03125f,
        (long)S * H, (long)S * H, (long)S * S);

    // Row softmax: 8192 rows of 2048
    softmax_rows<<<dim3(B * S), blk, 0, stream>>>(Sc, P);

    // O = P·Vtᵀ -> out (fp32)
    gemm256<3><<<dim3(H / BN, S / BM, B), blk512, LDS_TOTAL, stream>>>(
        P, Vt, nullptr, nullptr, nullptr, out, S, H, 1.0f,
        (long)S * S, (long)H * S, (long)S * H);
}

// Round 2
// 288.781 us; speedup vs baseline: 1.0482x; 1.0482x over previous
//
#include <hip/hip_runtime.h>
#include <cstdint>
#include <cstddef>

// Attention: B=4, S=2048, H=1024 (single "head", d=1024). fp32 I/O buffers.
// Pipeline: cvt x,W* to bf16 ; fused QKV GEMM (N=3072 -> Q,K,Vt) ;
//           Sc = Q·Kᵀ/32 (fp16) ; P = softmax(Sc) (bf16) ; out = P·Vtᵀ (fp32).
//
// R11: BK=64 256² 4-phase-per-K-tile schedule (fixes R10's regression):
//   - R10 post-mortem: custom pair-interleave swizzle produced 4.7M bank
//     conflicts (2-way dup per 8-lane group of ds_read_b128); MfmaUtil 21%.
//   - Swizzle now = R6/R9-proven (measured 0 conflicts, same read pattern):
//     [row][128B] rows, slot = chunk ^ (row&7).  BK=64 -> row = exactly 128B.
//     DMA dest linear; global source inverse-permuted (same involution).
//   - 8 waves (512 thr) 2M x 4N, per-wave 128x64 out (acc[8][4]).
//   - LDS: A[2 dbuf][32KB] + B[2][32KB] = 128KB.  K-tile t reads dbuf t&1.
//   - 4 phases per K-tile, 16 MFMA each (quadrants: (mh0,nh0)(mh0,nh1)
//     (mh1,nh1)(mh1,nh0)); ds_reads per phase 12/4/8/4.
//   - Stage plan (race-free by barrier semantics):
//       P0: B-h0 of t+1 -> B[d^1]   (B[d^1] last read in t-1; all waves past
//                                    that boundary barrier before issue)
//       P1: B-h1 of t+1 -> B[d^1]
//       P3: A-h0+h1 of t+2 -> A[d]  (A[d] read only in P0/P2; all waves past
//                                    P2's closing barrier before issue)
//     Boundary: s_waitcnt vmcnt(4); s_barrier  -- leaves only the P3 A-pair
//     (needed 5 phases later) in flight; guarantees tile t+1 fully landed.
//     Tail: vmcnt(0) at t==NT-2; nothing after last tile.
//   - setprio(1) around each 16-MFMA cluster (T5; pays in phase-split sched).
//
// ws layout (102 MB): [0,16M) xb ; [16,22M) Wqkv bf16 (Wq|Wk|Wv) ;
//   [22,38M) Q ; [38,54M) Kp ; [54,70M) Vt ; [70,102M) Sc fp16 ;
//   P overlays [22,54M) (Q|Kp dead after scores GEMM).

typedef __bf16 bf16;
typedef _Float16 f16;
typedef __bf16 bf16x8 __attribute__((ext_vector_type(8)));
typedef __bf16 bf16x4 __attribute__((ext_vector_type(4)));
typedef _Float16 f16x8 __attribute__((ext_vector_type(8)));
typedef float f32x4 __attribute__((ext_vector_type(4)));

#define BM 256
#define BN 256
#define BKT 64
#define LDS_TOTAL 131072

// Fused fp32->bf16 convert: x (XQ quads) -> xb, then Wq|Wk|Wv (WQ quads each)
// -> contiguous Wqkv. One dispatch.
#define XQ (8388608 / 4)
#define WQ (1048576 / 4)
__global__ __launch_bounds__(256)
void cvt_all(const float* __restrict__ x, const float* __restrict__ Wq,
             const float* __restrict__ Wk, const float* __restrict__ Wv,
             bf16* __restrict__ xb, bf16* __restrict__ Wqkv)
{
    const int i = blockIdx.x * 256 + threadIdx.x;
    const float* src;
    bf16* dst;
    if (i < XQ) {
        src = x + 4 * (size_t)i;
        dst = xb + 4 * (size_t)i;
    } else {
        const int j = i - XQ;                 // 0 .. 3*WQ-1
        const int w = j / WQ;                 // 0..2
        const int off = j - w * WQ;
        const float* ws_ = (w == 0) ? Wq : (w == 1) ? Wk : Wv;
        src = ws_ + 4 * (size_t)off;
        dst = Wqkv + 4 * (size_t)j;
    }
    f32x4 v = *(const f32x4*)src;
    bf16x4 o;
#pragma unroll
    for (int r = 0; r < 4; ++r) o[r] = (bf16)v[r];
    *(bf16x4*)dst = o;
}

// OUTMODE: 2 = f16 out, scaled by alpha (scores)
//          3 = f32 out (final O -> d_out)
//          4 = fused QKV: col3>>10 selects {Q,K,Vt}; bias0/1/2 = bq/bk/bv.
template <int OUTMODE>
__global__ __launch_bounds__(512, 2)
void gemm256(const bf16* __restrict__ A, const bf16* __restrict__ Bm,
             const float* __restrict__ bias0, const float* __restrict__ bias1,
             const float* __restrict__ bias2, void* __restrict__ C,
             int K, int N, float alpha, long zA, long zB, long zC)
{
    extern __shared__ __align__(16) char smem[];
    auto lds3 = (__attribute__((address_space(3))) char*)smem;

    const int tid  = threadIdx.x;
    const int lane = tid & 63;
    const int wid  = tid >> 6;
    const int quad = lane >> 4;
    const int l16  = lane & 15;
    const int wr   = (wid >> 2) * 128;   // wave row offset in 256 tile
    const int wc   = (wid & 3) * 64;     // wave col offset in 256 tile

    const int m0 = blockIdx.y * BM;
    const int n0 = blockIdx.x * BN;
    const int z  = blockIdx.z;

    const bf16* Ab = A + (size_t)z * zA + (size_t)m0 * K;
    const bf16* Bb = Bm + (size_t)z * zB + (size_t)n0 * K;

    // DMA: dest is linear (slot s = issue*512 + tid); source inverse-permuted
    // so slot (r, p) receives global chunk p ^ (r&7).
    const int sr  = tid >> 3;                    // row 0..63 (issue 0)
    const int sc  = (tid & 7) ^ (sr & 7);        // source chunk for this slot
    const size_t soff = (size_t)sr * K + (size_t)sc * 8;
    const long  hstep = 64L * K;                 // issue-1 covers rows +64
    const long  h1off = 128L * K;                // half-1 global row offset
    const unsigned dmabase = (unsigned)(wid * 1024);

#define STAGE(g, ldsoff)                                                       \
    do {                                                                       \
        __builtin_amdgcn_global_load_lds(                                      \
            (const __attribute__((address_space(1))) void*)((g) + soff),       \
            (__attribute__((address_space(3))) void*)(lds3 + (ldsoff) + dmabase), \
            16, 0, 0);                                                         \
        __builtin_amdgcn_global_load_lds(                                      \
            (const __attribute__((address_space(1))) void*)((g) + soff + hstep), \
            (__attribute__((address_space(3))) void*)(lds3 + (ldsoff) + 8192 + dmabase), \
            16, 0, 0);                                                         \
    } while (0)

    // LDS read bases. A-half = wid>>2 (wave reads rows wr..wr+127);
    // B-half = (wid&3)>>1, within-half base row = ((wid&3)&1)*64.
    // frag (i, kk): addr = base + i*2048 + ((kk*4+quad) ^ (l16&7))*16,
    // and (kk=1 slot) = (kk=0 slot) ^ 4  ->  byte ^ 64.
    const char* pa = (const char*)smem + (wid >> 2) * 16384 + l16 * 128;
    const char* pb = (const char*)smem + 65536 + ((wid & 3) >> 1) * 16384 +
                     (((wid & 3) & 1) * 64 + l16) * 128;
    const int x0 = (quad ^ (l16 & 7)) * 16;

    const int NT = K / BKT;
    f32x4 acc[8][4] = {};
    bf16x8 af[4][2], b01[2][2], b23[2][2];

    // prologue: A0(h0,h1), B0(h0,h1), A1(h0,h1); wait first 4 halves landed.
    STAGE(Ab, 0u);             STAGE(Ab + h1off, 16384u);
    STAGE(Bb, 65536u);         STAGE(Bb + h1off, 65536u + 16384u);
    STAGE(Ab + 64, 32768u);    STAGE(Ab + 64 + h1off, 32768u + 16384u);
    asm volatile("s_waitcnt vmcnt(4)\n\ts_barrier" ::: "memory");

    for (int t = 0; t < NT; ++t) {
        const int d  = (t & 1) * 32768;
        const int dn = 32768 - d;          // other dbuf
        const char* paT = pa + d;
        const char* pbT = pb + d;

        // ---- P0: quadrant (mh0, nh0); reads af0-3 + b01 (12) ----
#pragma unroll
        for (int i = 0; i < 4; ++i) {
            af[i][0] = *(const bf16x8*)(paT + i * 2048 + x0);
            af[i][1] = *(const bf16x8*)(paT + i * 2048 + (x0 ^ 64));
        }
#pragma unroll
        for (int j = 0; j < 2; ++j) {
            b01[j][0] = *(const bf16x8*)(pbT + j * 2048 + x0);
            b01[j][1] = *(const bf16x8*)(pbT + j * 2048 + (x0 ^ 64));
        }
        if (t + 1 < NT) STAGE(Bb + (t + 1) * 64, 65536u + dn);
        asm volatile("s_barrier\n\ts_waitcnt lgkmcnt(0)" ::: "memory");
        __builtin_amdgcn_s_setprio(1);
#pragma unroll
        for (int i = 0; i < 4; ++i)
#pragma unroll
            for (int j = 0; j < 2; ++j) {
                acc[i][j] = __builtin_amdgcn_mfma_f32_16x16x32_bf16(
                    af[i][0], b01[j][0], acc[i][j], 0, 0, 0);
                acc[i][j] = __builtin_amdgcn_mfma_f32_16x16x32_bf16(
                    af[i][1], b01[j][1], acc[i][j], 0, 0, 0);
            }
        __builtin_amdgcn_s_setprio(0);
        asm volatile("s_barrier" ::: "memory");

        // ---- P1: quadrant (mh0, nh1); reads b23 (4) ----
#pragma unroll
        for (int j = 0; j < 2; ++j) {
            b23[j][0] = *(const bf16x8*)(pbT + (2 + j) * 2048 + x0);
            b23[j][1] = *(const bf16x8*)(pbT + (2 + j) * 2048 + (x0 ^ 64));
        }
        if (t + 1 < NT) STAGE(Bb + (t + 1) * 64 + h1off, 65536u + dn + 16384u);
        asm volatile("s_barrier\n\ts_waitcnt lgkmcnt(0)" ::: "memory");
        __builtin_amdgcn_s_setprio(1);
#pragma unroll
        for (int i = 0; i < 4; ++i)
#pragma unroll
            for (int j = 0; j < 2; ++j) {
                acc[i][2 + j] = __builtin_amdgcn_mfma_f32_16x16x32_bf16(
                    af[i][0], b23[j][0], acc[i][2 + j], 0, 0, 0);
                acc[i][2 + j] = __builtin_amdgcn_mfma_f32_16x16x32_bf16(
                    af[i][1], b23[j][1], acc[i][2 + j], 0, 0, 0);
            }
        __builtin_amdgcn_s_setprio(0);
        asm volatile("s_barrier" ::: "memory");

        // ---- P2: quadrant (mh1, nh1); reads af4-7 (8) ----
#pragma unroll
        for (int i = 0; i < 4; ++i) {
            af[i][0] = *(const bf16x8*)(paT + (4 + i) * 2048 + x0);
            af[i][1] = *(const bf16x8*)(paT + (4 + i) * 2048 + (x0 ^ 64));
        }
        asm volatile("s_barrier\n\ts_waitcnt lgkmcnt(0)" ::: "memory");
        __builtin_amdgcn_s_setprio(1);
#pragma unroll
        for (int i = 0; i < 4; ++i)
#pragma unroll
            for (int j = 0; j < 2; ++j) {
                acc[4 + i][2 + j] = __builtin_amdgcn_mfma_f32_16x16x32_bf16(
                    af[i][0], b23[j][0], acc[4 + i][2 + j], 0, 0, 0);
                acc[4 + i][2 + j] = __builtin_amdgcn_mfma_f32_16x16x32_bf16(
                    af[i][1], b23[j][1], acc[4 + i][2 + j], 0, 0, 0);
            }
        __builtin_amdgcn_s_setprio(0);
        asm volatile("s_barrier" ::: "memory");

        // ---- P3: quadrant (mh1, nh0); reads b01 again (4) ----
#pragma unroll
        for (int j = 0; j < 2; ++j) {
            b01[j][0] = *(const bf16x8*)(pbT + j * 2048 + x0);
            b01[j][1] = *(const bf16x8*)(pbT + j * 2048 + (x0 ^ 64));
        }
        if (t + 2 < NT) {   // A[d] free: its reads ended at P2's closing barrier
            STAGE(Ab + (t + 2) * 64, (unsigned)d);
            STAGE(Ab + (t + 2) * 64 + h1off, (unsigned)d + 16384u);
        }
        asm volatile("s_barrier\n\ts_waitcnt lgkmcnt(0)" ::: "memory");
        __builtin_amdgcn_s_setprio(1);
#pragma unroll
        for (int i = 0; i < 4; ++i)
#pragma unroll
            for (int j = 0; j < 2; ++j) {
                acc[4 + i][j] = __builtin_amdgcn_mfma_f32_16x16x32_bf16(
                    af[i][0], b01[j][0], acc[4 + i][j], 0, 0, 0);
                acc[4 + i][j] = __builtin_amdgcn_mfma_f32_16x16x32_bf16(
                    af[i][1], b01[j][1], acc[4 + i][j], 0, 0, 0);
            }
        __builtin_amdgcn_s_setprio(0);
        // K-tile boundary: counted landing guarantee fused with the barrier.
        if (t + 2 < NT)
            asm volatile("s_waitcnt vmcnt(4)\n\ts_barrier" ::: "memory");
        else if (t + 1 < NT)
            asm volatile("s_waitcnt vmcnt(0)\n\ts_barrier" ::: "memory");
    }
#undef STAGE

    // Epilogue. C/D layout (verified m89): col = lane&15, row = quad*4 + reg.
#pragma unroll
    for (int j = 0; j < 4; ++j) {
        const int col3 = n0 + wc + j * 16 + l16;
#pragma unroll
        for (int i = 0; i < 8; ++i) {
            const int rbase = m0 + wr + i * 16 + quad * 4;
            if (OUTMODE == 2) {
                f16* Cf = (f16*)C + (size_t)z * zC;
#pragma unroll
                for (int r = 0; r < 4; ++r)
                    Cf[(size_t)(rbase + r) * N + col3] = (f16)(acc[i][j][r] * alpha);
            } else if (OUTMODE == 3) {
                float* Cf = (float*)C + (size_t)z * zC;
#pragma unroll
                for (int r = 0; r < 4; ++r)
                    Cf[(size_t)(rbase + r) * N + col3] = acc[i][j][r];
            } else { // OUTMODE == 4
                const int mat = col3 >> 10;           // 0=Q 1=K 2=V
                const int col = col3 & 1023;
                const float* bp = (mat == 0) ? bias0 : (mat == 1) ? bias1 : bias2;
                const float bj = bp[col];
                if (mat < 2) {
                    bf16* Cb = (bf16*)C + (size_t)mat * (8u << 20);
#pragma unroll
                    for (int r = 0; r < 4; ++r)
                        Cb[(size_t)(rbase + r) * 1024 + col] =
                            (bf16)(acc[i][j][r] + bj);
                } else {
                    // Vt[b][col][s] = V[b*2048+s][col]; quad rows are 4
                    // consecutive s -> one 8B same-type vector store.
                    bf16* Cb = (bf16*)C + (size_t)(16u << 20);
                    const int b = rbase >> 11;
                    const int s = rbase & 2047;
                    bf16x4 tmp;
#pragma unroll
                    for (int r = 0; r < 4; ++r) tmp[r] = (bf16)(acc[i][j][r] + bj);
                    *(bf16x4*)(Cb + (((size_t)((b << 10) + col)) << 11) + s) = tmp;
                }
            }
        }
    }
}

__device__ __forceinline__ float wred_max(float v)
{
#pragma unroll
    for (int o = 32; o > 0; o >>= 1) v = fmaxf(v, __shfl_xor(v, o, 64));
    return v;
}
__device__ __forceinline__ float wred_sum(float v)
{
#pragma unroll
    for (int o = 32; o > 0; o >>= 1) v += __shfl_xor(v, o, 64);
    return v;
}

__global__ __launch_bounds__(256)
void softmax_rows(const f16* __restrict__ Sc, bf16* __restrict__ P)
{
    constexpr int NC = 2048;
    const size_t row = blockIdx.x;
    const f16* src = Sc + row * NC;
    bf16* dst = P + row * NC;
    const int tid = threadIdx.x;

    f16x8 in = *(const f16x8*)(src + tid * 8);
    float v[8];
    float m = -3.4e38f;
#pragma unroll
    for (int i = 0; i < 8; ++i) {
        v[i] = (float)in[i];
        m = fmaxf(m, v[i]);
    }
    m = wred_max(m);

    __shared__ float redm[4], reds[4];
    if ((tid & 63) == 0) redm[tid >> 6] = m;
    __syncthreads();
    m = fmaxf(fmaxf(redm[0], redm[1]), fmaxf(redm[2], redm[3]));

    float s = 0.f;
#pragma unroll
    for (int i = 0; i < 8; ++i) { v[i] = __expf(v[i] - m); s += v[i]; }
    s = wred_sum(s);
    if ((tid & 63) == 0) reds[tid >> 6] = s;
    __syncthreads();
    s = reds[0] + reds[1] + reds[2] + reds[3];

    const float inv = 1.f / s;
    bf16x8 o;
#pragma unroll
    for (int i = 0; i < 8; ++i) o[i] = (bf16)(v[i] * inv);
    *(bf16x8*)(dst + tid * 8) = o;
}

extern "C" void kernel_launch(void* const* d_in, const int* in_sizes, int n_in,
                              void* d_out, int out_size, void* d_ws, size_t ws_size,
                              hipStream_t stream)
{
    constexpr int B = 4, S = 2048, H = 1024;
    const float* x  = (const float*)d_in[0];
    const float* Wq = (const float*)d_in[1];
    const float* bq = (const float*)d_in[2];
    const float* Wk = (const float*)d_in[3];
    const float* bk = (const float*)d_in[4];
    const float* Wv = (const float*)d_in[5];
    const float* bv = (const float*)d_in[6];
    float* out = (float*)d_out;

    char* ws = (char*)d_ws;
    bf16* xb   = (bf16*)ws;                         // 16 MB
    bf16* Wqkv = (bf16*)(ws + (size_t)(16 << 20));  //  6 MB (Wq|Wk|Wv bf16)
    bf16* Q    = (bf16*)(ws + (size_t)(22 << 20));  // 16 MB
    bf16* Kp   = (bf16*)(ws + (size_t)(38 << 20));  // 16 MB
    bf16* Vt   = (bf16*)(ws + (size_t)(54 << 20));  // 16 MB
    f16*  Sc   = (f16*) (ws + (size_t)(70 << 20));  // 32 MB (fp16 scores)
    bf16* P    = (bf16*)(ws + (size_t)(22 << 20));  // 32 MB, overlays Q|Kp

    static bool attr_done = false;
    if (!attr_done) {
        attr_done = true;
        (void)hipFuncSetAttribute(reinterpret_cast<const void*>(gemm256<4>),
                                  hipFuncAttributeMaxDynamicSharedMemorySize,
                                  LDS_TOTAL);
        (void)hipFuncSetAttribute(reinterpret_cast<const void*>(gemm256<2>),
                                  hipFuncAttributeMaxDynamicSharedMemorySize,
                                  LDS_TOTAL);
        (void)hipFuncSetAttribute(reinterpret_cast<const void*>(gemm256<3>),
                                  hipFuncAttributeMaxDynamicSharedMemorySize,
                                  LDS_TOTAL);
    }

    dim3 blk(256, 1, 1);
    dim3 blk512(512, 1, 1);

    // fp32 -> bf16 conversions, one dispatch (x -> xb, Wq|Wk|Wv -> Wqkv)
    cvt_all<<<dim3((XQ + 3 * WQ) / 256), blk, 0, stream>>>(
        x, Wq, Wk, Wv, xb, Wqkv);

    // Fused QKV projection: M = 8192, N = 3072, K = 1024 -> Q, Kp, Vt
    gemm256<4><<<dim3(3 * H / BN, (B * S) / BM, 1), blk512, LDS_TOTAL, stream>>>(
        xb, Wqkv, bq, bk, bv, Q, H, 3 * H, 1.0f, 0, 0, 0);

    // Scores: per batch (grid.z), Sc = Q·Kᵀ / 32, fp16
    gemm256<2><<<dim3(S / BN, S / BM, B), blk512, LDS_TOTAL, stream>>>(
        Q, Kp, nullptr, nullptr, nullptr, Sc, H, S, 0.03125f,
        (long)S * H, (long)S * H, (long)S * S);

    // Row softmax: 8192 rows of 2048
    softmax_rows<<<dim3(B * S), blk, 0, stream>>>(Sc, P);

    // O = P·Vtᵀ -> out (fp32)
    gemm256<3><<<dim3(H / BN, S / BM, B), blk512, LDS_TOTAL, stream>>>(
        P, Vt, nullptr, nullptr, nullptr, out, S, H, 1.0f,
        (long)S * S, (long)H * S, (long)S * H);
}

// Round 4
// 248.505 us; speedup vs baseline: 1.2180x; 1.1621x over previous
//
#include <hip/hip_runtime.h>
#include <cstdint>
#include <cstddef>

// Attention: B=4, S=2048, H=1024 (single "head", d=1024). fp32 I/O buffers.
// Pipeline: cvt x,W* to bf16 ; fused QKV GEMM (N=3072 -> Q,K,Vt) ;
//           Sc = Q·Kᵀ/32 (fp16) ; P = softmax(Sc) (bf16) ; out = P·Vtᵀ (fp32).
//
// R13 == R12 resubmit (R12 bench died at container acquire, no kernel verdict;
// OOB/hang audit re-done: all barriers uniform, all LDS/global extents in
// bounds, race proof re-verified load-by-load).
//
// R12: minimal-barrier "drift" schedule (R11 post-mortem: 9 barriers/K-tile
// serialized every wave's ds_read window against every wave's MFMA window ->
// MfmaUtil 23%; per-tile wall 8700cyc vs 2500 MFMA + ~2000 LDS).
//   Only the barriers PROVABLY needed for buffer rotation:
//   - boundary barrier (fused with counted vmcnt) once per K-tile;
//   - one mid-tile barrier before the A-restage (NW_N=4 path only).
//   Waves drift between barriers -> ds_read of one wave overlaps MFMA of
//   another (m114); compiler emits fine-grained lgkmcnt for its own deps.
//   vmcnt per wave (steady state, NW_N=4): issues/tile P0 B-h0(2), P1 B-h1(2),
//     P3 A(t+2)(4); boundary outstanding = [A(t+1)x4, B(t+1)x4, A(t+2)x4]=12
//     -> vmcnt(4) drains A(t+1)+B(t+1), keeps A(t+2).  Tail vmcnt(0) at NT-2.
//   PV variant NW_N=2 (BN=128): grid 128->256 blocks (was half-GPU idle).
//     A 3-buf (3x32KB) + B dbuf (2x16KB) = 128KB -> NO mid barrier
//     (A[(t+2)%3] untouched by tiles t,t+1).  vmcnt: [4+2+4]=10 -> vmcnt(4).
//   T1 XCD swizzle (m204 bijective; all grids %8==0) for A-panel L2 sharing.
//
// LDS swizzle (R6/R11-proven, 0 conflicts): [row][128B] rows, 16B slot
//   slot = chunk ^ (row&7); DMA dest linear, global source inverse-permuted.
//
// ws layout (102 MB): [0,16M) xb ; [16,22M) Wqkv bf16 (Wq|Wk|Wv) ;
//   [22,38M) Q ; [38,54M) Kp ; [54,70M) Vt ; [70,102M) Sc fp16 ;
//   P overlays [22,54M) (Q|Kp dead after scores GEMM).

typedef __bf16 bf16;
typedef _Float16 f16;
typedef __bf16 bf16x8 __attribute__((ext_vector_type(8)));
typedef __bf16 bf16x4 __attribute__((ext_vector_type(4)));
typedef _Float16 f16x8 __attribute__((ext_vector_type(8)));
typedef float f32x4 __attribute__((ext_vector_type(4)));

#define BM 256
#define BKT 64
#define LDS_TOTAL 131072

// Fused fp32->bf16 convert: x (XQ quads) -> xb, then Wq|Wk|Wv (WQ quads each)
// -> contiguous Wqkv. One dispatch.
#define XQ (8388608 / 4)
#define WQ (1048576 / 4)
__global__ __launch_bounds__(256)
void cvt_all(const float* __restrict__ x, const float* __restrict__ Wq,
             const float* __restrict__ Wk, const float* __restrict__ Wv,
             bf16* __restrict__ xb, bf16* __restrict__ Wqkv)
{
    const int i = blockIdx.x * 256 + threadIdx.x;
    const float* src;
    bf16* dst;
    if (i < XQ) {
        src = x + 4 * (size_t)i;
        dst = xb + 4 * (size_t)i;
    } else {
        const int j = i - XQ;                 // 0 .. 3*WQ-1
        const int w = j / WQ;                 // 0..2
        const int off = j - w * WQ;
        const float* ws_ = (w == 0) ? Wq : (w == 1) ? Wk : Wv;
        src = ws_ + 4 * (size_t)off;
        dst = Wqkv + 4 * (size_t)j;
    }
    f32x4 v = *(const f32x4*)src;
    bf16x4 o;
#pragma unroll
    for (int r = 0; r < 4; ++r) o[r] = (bf16)v[r];
    *(bf16x4*)dst = o;
}

// OUTMODE: 2 = f16 out, scaled by alpha (scores)
//          3 = f32 out (final O -> d_out)
//          4 = fused QKV: col3>>10 selects {Q,K,Vt}; bias0/1/2 = bq/bk/bv.
// NW_N: waves along N. 4 -> BN=256 (wave grid 2Mx4N, acc[8][4]);
//                      2 -> BN=128 (wave grid 4Mx2N, acc[4][4], A 3-buf).
template <int OUTMODE, int NW_N>
__global__ __launch_bounds__(512, 2)
void gemm256(const bf16* __restrict__ A, const bf16* __restrict__ Bm,
             const float* __restrict__ bias0, const float* __restrict__ bias1,
             const float* __restrict__ bias2, void* __restrict__ C,
             int K, int N, float alpha, long zA, long zB, long zC)
{
    constexpr int MI = 2 * NW_N;          // A-frags per wave (8 or 4)
    extern __shared__ __align__(16) char smem[];
    auto lds3 = (__attribute__((address_space(3))) char*)smem;

    const int tid  = threadIdx.x;
    const int lane = tid & 63;
    const int wid  = tid >> 6;
    const int quad = lane >> 4;
    const int l16  = lane & 15;
    const int wc   = (wid % NW_N) * 64;         // wave col offset in tile
    const int wr   = (wid / NW_N) * (MI * 16);  // wave row offset in tile

    // T1: bijective XCD swizzle (all our grids have nwg % 8 == 0).
    const unsigned gx = gridDim.x, gy = gridDim.y;
    unsigned flat = blockIdx.x + gx * (blockIdx.y + gy * blockIdx.z);
    const unsigned chunk = (gx * gy * gridDim.z) >> 3;
    flat = (flat & 7u) * chunk + (flat >> 3);
    const int bx = flat % gx;
    const unsigned r2 = flat / gx;
    const int by = r2 % gy;
    const int z  = r2 / gy;

    const int m0 = by * BM;
    const int n0 = bx * (NW_N * 64);

    const bf16* Ab = A + (size_t)z * zA + (size_t)m0 * K;
    const bf16* Bb = Bm + (size_t)z * zB + (size_t)n0 * K;

    // DMA: dest linear (slot s = issue*512 + tid); source inverse-permuted so
    // slot (r, p) receives global chunk p ^ (r&7).
    const int sr  = tid >> 3;                    // row 0..63 (issue 0)
    const int sc  = (tid & 7) ^ (sr & 7);        // source chunk for this slot
    const size_t soff = (size_t)sr * K + (size_t)sc * 8;
    const long  hstep = 64L * K;                 // issue-1 covers rows +64
    const long  h1off = 128L * K;                // half-1 global row offset
    const unsigned dmabase = (unsigned)(wid * 1024);

#define STAGE(g, ldsoff)                                                       \
    do {                                                                       \
        __builtin_amdgcn_global_load_lds(                                      \
            (const __attribute__((address_space(1))) void*)((g) + soff),       \
            (__attribute__((address_space(3))) void*)(lds3 + (ldsoff) + dmabase), \
            16, 0, 0);                                                         \
        __builtin_amdgcn_global_load_lds(                                      \
            (const __attribute__((address_space(1))) void*)((g) + soff + hstep), \
            (__attribute__((address_space(3))) void*)(lds3 + (ldsoff) + 8192 + dmabase), \
            16, 0, 0);                                                         \
    } while (0)

    // Fragment read bases. frag (i,kk): byte = base + i*2048 + slot*16,
    // slot = (kk*4+quad) ^ (l16&7); kk=1 slot = kk=0 slot ^ 4 -> byte ^ 64.
    const char* pa = (const char*)smem + (wr + l16) * 128;
    const int x0 = (quad ^ (l16 & 7)) * 16;

    const int NT = K / BKT;
    f32x4 acc[MI][4] = {};

    if constexpr (NW_N == 4) {
        // LDS: A dbuf @0/32768 ; B dbuf @65536/98304.
        const char* pb = (const char*)smem + 65536 + (wc + l16) * 128;
        bf16x8 af[4][2], b01[2][2], b23[2][2];

        // prologue: A0, B0, A1 (12 loads); vmcnt(4) -> A0+B0 landed.
        STAGE(Ab, 0u);           STAGE(Ab + h1off, 16384u);
        STAGE(Bb, 65536u);       STAGE(Bb + h1off, 65536u + 16384u);
        STAGE(Ab + 64, 32768u);  STAGE(Ab + 64 + h1off, 32768u + 16384u);
        asm volatile("s_waitcnt vmcnt(4)\n\ts_barrier" ::: "memory");

        for (int t = 0; t < NT; ++t) {
            const unsigned d  = (unsigned)(t & 1) * 32768u;
            const unsigned dn = 32768u - d;
            const char* paT = pa + d;
            const char* pbT = pb + d;

            // P0: af0-3 + b01 ; stage B-h0(t+1)
#pragma unroll
            for (int i = 0; i < 4; ++i) {
                af[i][0] = *(const bf16x8*)(paT + i * 2048 + x0);
                af[i][1] = *(const bf16x8*)(paT + i * 2048 + (x0 ^ 64));
            }
#pragma unroll
            for (int j = 0; j < 2; ++j) {
                b01[j][0] = *(const bf16x8*)(pbT + j * 2048 + x0);
                b01[j][1] = *(const bf16x8*)(pbT + j * 2048 + (x0 ^ 64));
            }
            if (t + 1 < NT) STAGE(Bb + (t + 1) * 64, 65536u + dn);
            __builtin_amdgcn_s_setprio(1);
#pragma unroll
            for (int i = 0; i < 4; ++i)
#pragma unroll
                for (int j = 0; j < 2; ++j) {
                    acc[i][j] = __builtin_amdgcn_mfma_f32_16x16x32_bf16(
                        af[i][0], b01[j][0], acc[i][j], 0, 0, 0);
                    acc[i][j] = __builtin_amdgcn_mfma_f32_16x16x32_bf16(
                        af[i][1], b01[j][1], acc[i][j], 0, 0, 0);
                }
            __builtin_amdgcn_s_setprio(0);

            // P1: b23 ; stage B-h1(t+1)
#pragma unroll
            for (int j = 0; j < 2; ++j) {
                b23[j][0] = *(const bf16x8*)(pbT + (2 + j) * 2048 + x0);
                b23[j][1] = *(const bf16x8*)(pbT + (2 + j) * 2048 + (x0 ^ 64));
            }
            if (t + 1 < NT) STAGE(Bb + (t + 1) * 64 + h1off, 65536u + dn + 16384u);
            __builtin_amdgcn_s_setprio(1);
#pragma unroll
            for (int i = 0; i < 4; ++i)
#pragma unroll
                for (int j = 0; j < 2; ++j) {
                    acc[i][2 + j] = __builtin_amdgcn_mfma_f32_16x16x32_bf16(
                        af[i][0], b23[j][0], acc[i][2 + j], 0, 0, 0);
                    acc[i][2 + j] = __builtin_amdgcn_mfma_f32_16x16x32_bf16(
                        af[i][1], b23[j][1], acc[i][2 + j], 0, 0, 0);
                }
            __builtin_amdgcn_s_setprio(0);

            // P2: af4-7
#pragma unroll
            for (int i = 0; i < 4; ++i) {
                af[i][0] = *(const bf16x8*)(paT + (4 + i) * 2048 + x0);
                af[i][1] = *(const bf16x8*)(paT + (4 + i) * 2048 + (x0 ^ 64));
            }
            __builtin_amdgcn_s_setprio(1);
#pragma unroll
            for (int i = 0; i < 4; ++i)
#pragma unroll
                for (int j = 0; j < 2; ++j) {
                    acc[4 + i][2 + j] = __builtin_amdgcn_mfma_f32_16x16x32_bf16(
                        af[i][0], b23[j][0], acc[4 + i][2 + j], 0, 0, 0);
                    acc[4 + i][2 + j] = __builtin_amdgcn_mfma_f32_16x16x32_bf16(
                        af[i][1], b23[j][1], acc[4 + i][2 + j], 0, 0, 0);
                }
            __builtin_amdgcn_s_setprio(0);

            // mid barrier: A[d] fully consumed by every wave (its reads
            // complete before P0/P2 MFMAs, which precede this barrier).
            asm volatile("s_barrier" ::: "memory");

            // P3: b01 re-read ; stage A(t+2) -> A[d]
#pragma unroll
            for (int j = 0; j < 2; ++j) {
                b01[j][0] = *(const bf16x8*)(pbT + j * 2048 + x0);
                b01[j][1] = *(const bf16x8*)(pbT + j * 2048 + (x0 ^ 64));
            }
            if (t + 2 < NT) {
                STAGE(Ab + (t + 2) * 64, d);
                STAGE(Ab + (t + 2) * 64 + h1off, d + 16384u);
            }
            __builtin_amdgcn_s_setprio(1);
#pragma unroll
            for (int i = 0; i < 4; ++i)
#pragma unroll
                for (int j = 0; j < 2; ++j) {
                    acc[4 + i][j] = __builtin_amdgcn_mfma_f32_16x16x32_bf16(
                        af[i][0], b01[j][0], acc[4 + i][j], 0, 0, 0);
                    acc[4 + i][j] = __builtin_amdgcn_mfma_f32_16x16x32_bf16(
                        af[i][1], b01[j][1], acc[4 + i][j], 0, 0, 0);
                }
            __builtin_amdgcn_s_setprio(0);

            // boundary: counted landing guarantee fused with the barrier.
            if (t + 2 < NT)
                asm volatile("s_waitcnt vmcnt(4)\n\ts_barrier" ::: "memory");
            else if (t + 1 < NT)
                asm volatile("s_waitcnt vmcnt(0)\n\ts_barrier" ::: "memory");
        }
    } else {
        // NW_N == 2: A 3-buf @0/32768/65536 ; B dbuf @98304/114688.
        bf16x8 af[2][2], bfr[4][2];

        // prologue: A0 (4), B0 (2), A1 (4); vmcnt(4) -> A0+B0 landed.
        STAGE(Ab, 0u);           STAGE(Ab + h1off, 16384u);
        STAGE(Bb, 98304u);
        STAGE(Ab + 64, 32768u);  STAGE(Ab + 64 + h1off, 32768u + 16384u);
        asm volatile("s_waitcnt vmcnt(4)\n\ts_barrier" ::: "memory");

        for (int t = 0; t < NT; ++t) {
            const char* paT = pa + (unsigned)(t % 3) * 32768u;
            const char* pbT = (const char*)smem + 98304u +
                              (unsigned)(t & 1) * 16384u + (wc + l16) * 128;

            // P0: af0-1 + all bf ; stage B(t+1)
#pragma unroll
            for (int i = 0; i < 2; ++i) {
                af[i][0] = *(const bf16x8*)(paT + i * 2048 + x0);
                af[i][1] = *(const bf16x8*)(paT + i * 2048 + (x0 ^ 64));
            }
#pragma unroll
            for (int j = 0; j < 4; ++j) {
                bfr[j][0] = *(const bf16x8*)(pbT + j * 2048 + x0);
                bfr[j][1] = *(const bf16x8*)(pbT + j * 2048 + (x0 ^ 64));
            }
            if (t + 1 < NT)
                STAGE(Bb + (t + 1) * 64, 98304u + (unsigned)((t + 1) & 1) * 16384u);
            __builtin_amdgcn_s_setprio(1);
#pragma unroll
            for (int i = 0; i < 2; ++i)
#pragma unroll
                for (int j = 0; j < 4; ++j) {
                    acc[i][j] = __builtin_amdgcn_mfma_f32_16x16x32_bf16(
                        af[i][0], bfr[j][0], acc[i][j], 0, 0, 0);
                    acc[i][j] = __builtin_amdgcn_mfma_f32_16x16x32_bf16(
                        af[i][1], bfr[j][1], acc[i][j], 0, 0, 0);
                }
            __builtin_amdgcn_s_setprio(0);

            // P1: af2-3 ; stage A(t+2) -> A[(t+2)%3] (untouched by t, t+1)
#pragma unroll
            for (int i = 0; i < 2; ++i) {
                af[i][0] = *(const bf16x8*)(paT + (2 + i) * 2048 + x0);
                af[i][1] = *(const bf16x8*)(paT + (2 + i) * 2048 + (x0 ^ 64));
            }
            if (t + 2 < NT) {
                const unsigned da = (unsigned)((t + 2) % 3) * 32768u;
                STAGE(Ab + (t + 2) * 64, da);
                STAGE(Ab + (t + 2) * 64 + h1off, da + 16384u);
            }
            __builtin_amdgcn_s_setprio(1);
#pragma unroll
            for (int i = 0; i < 2; ++i)
#pragma unroll
                for (int j = 0; j < 4; ++j) {
                    acc[2 + i][j] = __builtin_amdgcn_mfma_f32_16x16x32_bf16(
                        af[i][0], bfr[j][0], acc[2 + i][j], 0, 0, 0);
                    acc[2 + i][j] = __builtin_amdgcn_mfma_f32_16x16x32_bf16(
                        af[i][1], bfr[j][1], acc[2 + i][j], 0, 0, 0);
                }
            __builtin_amdgcn_s_setprio(0);

            if (t + 2 < NT)
                asm volatile("s_waitcnt vmcnt(4)\n\ts_barrier" ::: "memory");
            else if (t + 1 < NT)
                asm volatile("s_waitcnt vmcnt(0)\n\ts_barrier" ::: "memory");
        }
    }
#undef STAGE

    // Epilogue. C/D layout (verified m89): col = lane&15, row = quad*4 + reg.
#pragma unroll
    for (int j = 0; j < 4; ++j) {
        const int col3 = n0 + wc + j * 16 + l16;
#pragma unroll
        for (int i = 0; i < MI; ++i) {
            const int rbase = m0 + wr + i * 16 + quad * 4;
            if (OUTMODE == 2) {
                f16* Cf = (f16*)C + (size_t)z * zC;
#pragma unroll
                for (int r = 0; r < 4; ++r)
                    Cf[(size_t)(rbase + r) * N + col3] = (f16)(acc[i][j][r] * alpha);
            } else if (OUTMODE == 3) {
                float* Cf = (float*)C + (size_t)z * zC;
#pragma unroll
                for (int r = 0; r < 4; ++r)
                    Cf[(size_t)(rbase + r) * N + col3] = acc[i][j][r];
            } else { // OUTMODE == 4
                const int mat = col3 >> 10;           // 0=Q 1=K 2=V
                const int col = col3 & 1023;
                const float* bp = (mat == 0) ? bias0 : (mat == 1) ? bias1 : bias2;
                const float bj = bp[col];
                if (mat < 2) {
                    bf16* Cb = (bf16*)C + (size_t)mat * (8u << 20);
#pragma unroll
                    for (int r = 0; r < 4; ++r)
                        Cb[(size_t)(rbase + r) * 1024 + col] =
                            (bf16)(acc[i][j][r] + bj);
                } else {
                    // Vt[b][col][s] = V[b*2048+s][col]; quad rows are 4
                    // consecutive s -> one 8B same-type vector store.
                    bf16* Cb = (bf16*)C + (size_t)(16u << 20);
                    const int b = rbase >> 11;
                    const int s = rbase & 2047;
                    bf16x4 tmp;
#pragma unroll
                    for (int r = 0; r < 4; ++r) tmp[r] = (bf16)(acc[i][j][r] + bj);
                    *(bf16x4*)(Cb + (((size_t)((b << 10) + col)) << 11) + s) = tmp;
                }
            }
        }
    }
}

__device__ __forceinline__ float wred_max(float v)
{
#pragma unroll
    for (int o = 32; o > 0; o >>= 1) v = fmaxf(v, __shfl_xor(v, o, 64));
    return v;
}
__device__ __forceinline__ float wred_sum(float v)
{
#pragma unroll
    for (int o = 32; o > 0; o >>= 1) v += __shfl_xor(v, o, 64);
    return v;
}

__global__ __launch_bounds__(256)
void softmax_rows(const f16* __restrict__ Sc, bf16* __restrict__ P)
{
    constexpr int NC = 2048;
    const size_t row = blockIdx.x;
    const f16* src = Sc + row * NC;
    bf16* dst = P + row * NC;
    const int tid = threadIdx.x;

    f16x8 in = *(const f16x8*)(src + tid * 8);
    float v[8];
    float m = -3.4e38f;
#pragma unroll
    for (int i = 0; i < 8; ++i) {
        v[i] = (float)in[i];
        m = fmaxf(m, v[i]);
    }
    m = wred_max(m);

    __shared__ float redm[4], reds[4];
    if ((tid & 63) == 0) redm[tid >> 6] = m;
    __syncthreads();
    m = fmaxf(fmaxf(redm[0], redm[1]), fmaxf(redm[2], redm[3]));

    float s = 0.f;
#pragma unroll
    for (int i = 0; i < 8; ++i) { v[i] = __expf(v[i] - m); s += v[i]; }
    s = wred_sum(s);
    if ((tid & 63) == 0) reds[tid >> 6] = s;
    __syncthreads();
    s = reds[0] + reds[1] + reds[2] + reds[3];

    const float inv = 1.f / s;
    bf16x8 o;
#pragma unroll
    for (int i = 0; i < 8; ++i) o[i] = (bf16)(v[i] * inv);
    *(bf16x8*)(dst + tid * 8) = o;
}

extern "C" void kernel_launch(void* const* d_in, const int* in_sizes, int n_in,
                              void* d_out, int out_size, void* d_ws, size_t ws_size,
                              hipStream_t stream)
{
    constexpr int B = 4, S = 2048, H = 1024;
    const float* x  = (const float*)d_in[0];
    const float* Wq = (const float*)d_in[1];
    const float* bq = (const float*)d_in[2];
    const float* Wk = (const float*)d_in[3];
    const float* bk = (const float*)d_in[4];
    const float* Wv = (const float*)d_in[5];
    const float* bv = (const float*)d_in[6];
    float* out = (float*)d_out;

    char* ws = (char*)d_ws;
    bf16* xb   = (bf16*)ws;                         // 16 MB
    bf16* Wqkv = (bf16*)(ws + (size_t)(16 << 20));  //  6 MB (Wq|Wk|Wv bf16)
    bf16* Q    = (bf16*)(ws + (size_t)(22 << 20));  // 16 MB
    bf16* Kp   = (bf16*)(ws + (size_t)(38 << 20));  // 16 MB
    bf16* Vt   = (bf16*)(ws + (size_t)(54 << 20));  // 16 MB
    f16*  Sc   = (f16*) (ws + (size_t)(70 << 20));  // 32 MB (fp16 scores)
    bf16* P    = (bf16*)(ws + (size_t)(22 << 20));  // 32 MB, overlays Q|Kp

    static bool attr_done = false;
    if (!attr_done) {
        attr_done = true;
        (void)hipFuncSetAttribute(reinterpret_cast<const void*>(gemm256<4, 4>),
                                  hipFuncAttributeMaxDynamicSharedMemorySize,
                                  LDS_TOTAL);
        (void)hipFuncSetAttribute(reinterpret_cast<const void*>(gemm256<2, 4>),
                                  hipFuncAttributeMaxDynamicSharedMemorySize,
                                  LDS_TOTAL);
        (void)hipFuncSetAttribute(reinterpret_cast<const void*>(gemm256<3, 2>),
                                  hipFuncAttributeMaxDynamicSharedMemorySize,
                                  LDS_TOTAL);
    }

    dim3 blk(256, 1, 1);
    dim3 blk512(512, 1, 1);

    // fp32 -> bf16 conversions, one dispatch (x -> xb, Wq|Wk|Wv -> Wqkv)
    cvt_all<<<dim3((XQ + 3 * WQ) / 256), blk, 0, stream>>>(
        x, Wq, Wk, Wv, xb, Wqkv);

    // Fused QKV projection: M = 8192, N = 3072, K = 1024 -> Q, Kp, Vt
    gemm256<4, 4><<<dim3(3 * H / 256, (B * S) / BM, 1), blk512, LDS_TOTAL, stream>>>(
        xb, Wqkv, bq, bk, bv, Q, H, 3 * H, 1.0f, 0, 0, 0);

    // Scores: per batch, Sc = Q·Kᵀ / 32, fp16  (grid 8x8x4 = 256)
    gemm256<2, 4><<<dim3(S / 256, S / BM, B), blk512, LDS_TOTAL, stream>>>(
        Q, Kp, nullptr, nullptr, nullptr, Sc, H, S, 0.03125f,
        (long)S * H, (long)S * H, (long)S * S);

    // Row softmax: 8192 rows of 2048
    softmax_rows<<<dim3(B * S), blk, 0, stream>>>(Sc, P);

    // O = P·Vtᵀ -> out (fp32)  (BN=128: grid 8x8x4 = 256, full GPU)
    gemm256<3, 2><<<dim3(H / 128, S / BM, B), blk512, LDS_TOTAL, stream>>>(
        P, Vt, nullptr, nullptr, nullptr, out, S, H, 1.0f,
        (long)S * S, (long)H * S, (long)S * H);
}

// Round 5
// 245.305 us; speedup vs baseline: 1.2339x; 1.0130x over previous
//
#include <hip/hip_runtime.h>
#include <cstdint>
#include <cstddef>

// Attention: B=4, S=2048, H=1024 (single "head", d=1024). fp32 I/O buffers.
// Pipeline: cvt x,W* to bf16 ; fused QKV GEMM (N=3072 -> Q,K,Vt) ;
//           Sc = Q·Kᵀ/32 (fp16) ; P = softmax(Sc) (bf16) ; out = P·Vtᵀ (fp32).
//
// R14: split strategies per dispatch based on R13 counters.
//   - QKV: REVERTED to the R0/R9-proven 128²/BK=64 dbuf gemm_bt (71.6µs
//     measured, MfmaUtil 29%).  The 256² ports (R10/R11/R13) measured 93/87/
//     104µs -- QKV's 384-block grid at 1 block/CU quantizes to 2 rounds (75%
//     util) and the re-derived schedules never matched m201's MfmaUtil.
//   - scores/PV: KEEP R13's 256² minimal-barrier drift gemm256 (these grids
//     are exactly 256 blocks = 1/CU; R13's residual shows they cut
//     scores+PV+overhead by ~45µs vs the 128² versions).
//   - softmax/cvt: unchanged (vectorized 16B I/O).
//
// gemm256 (scores/PV): drift schedule, barriers only for buffer rotation;
//   counted vmcnt(4) at K-tile boundaries (never 0 mid-loop); R6-proven LDS
//   swizzle slot = chunk ^ (row&7) (0 conflicts measured); T1 XCD swizzle.
//   NW_N=4: BN=256, A/B dbuf, 1 mid barrier (A-restage). NW_N=2: BN=128,
//   A 3-buf + B dbuf, no mid barrier.
//
// ws layout (102 MB): [0,16M) xb ; [16,22M) Wqkv bf16 (Wq|Wk|Wv) ;
//   [22,38M) Q ; [38,54M) Kp ; [54,70M) Vt ; [70,102M) Sc fp16 ;
//   P overlays [22,54M) (Q|Kp dead after scores GEMM).

typedef __bf16 bf16;
typedef _Float16 f16;
typedef __bf16 bf16x8 __attribute__((ext_vector_type(8)));
typedef __bf16 bf16x4 __attribute__((ext_vector_type(4)));
typedef _Float16 f16x8 __attribute__((ext_vector_type(8)));
typedef float f32x4 __attribute__((ext_vector_type(4)));

#define LDS_TOTAL 131072

// ---------------------------------------------------------------- cvt ------
#define XQ (8388608 / 4)
#define WQ (1048576 / 4)
__global__ __launch_bounds__(256)
void cvt_all(const float* __restrict__ x, const float* __restrict__ Wq,
             const float* __restrict__ Wk, const float* __restrict__ Wv,
             bf16* __restrict__ xb, bf16* __restrict__ Wqkv)
{
    const int i = blockIdx.x * 256 + threadIdx.x;
    const float* src;
    bf16* dst;
    if (i < XQ) {
        src = x + 4 * (size_t)i;
        dst = xb + 4 * (size_t)i;
    } else {
        const int j = i - XQ;                 // 0 .. 3*WQ-1
        const int w = j / WQ;                 // 0..2
        const int off = j - w * WQ;
        const float* ws_ = (w == 0) ? Wq : (w == 1) ? Wk : Wv;
        src = ws_ + 4 * (size_t)off;
        dst = Wqkv + 4 * (size_t)j;
    }
    f32x4 v = *(const f32x4*)src;
    bf16x4 o;
#pragma unroll
    for (int r = 0; r < 4; ++r) o[r] = (bf16)v[r];
    *(bf16x4*)dst = o;
}

// ------------------------------------------------- QKV: proven 128² gemm ---
#define BM1 128
#define BN1 128
#define BK1 64

// Stage one 128x64 bf16 tile (16 KB) global -> LDS via global_load_lds w=16.
// Lane at linear chunk p stores LDS slot p (DMA: wave-uniform base + lane*16,
// m104) and fetches global chunk (p&7)^(row&7) of row p>>3 (swizzle measured
// conflict-free in R6).
__device__ __forceinline__ void stage_tile(const bf16* __restrict__ g, int ld,
                                           bf16* lds_generic, int tid)
{
    auto lds3 = (__attribute__((address_space(3))) char*)lds_generic;
    const int wave = tid >> 6;
#pragma unroll
    for (int issue = 0; issue < 4; ++issue) {
        const int p   = issue * 256 + tid;
        const int row = p >> 3;
        const int cp  = p & 7;
        const int c   = cp ^ (row & 7);
        const bf16* gp = g + (size_t)row * ld + c * 8;
        const unsigned wave_base = (unsigned)(issue * 4096 + wave * 1024);
        __builtin_amdgcn_global_load_lds(
            (const __attribute__((address_space(1))) void*)gp,
            (__attribute__((address_space(3))) void*)(lds3 + wave_base),
            16, 0, 0);
    }
}

__device__ __forceinline__ bf16x8 read_frag(const bf16* lds, int row, int chunk)
{
    const int cp = chunk ^ (row & 7);
    return *(const bf16x8*)(lds + row * BK1 + cp * 8);
}

// OUTMODE 4 = fused QKV: col3>>10 selects {Q,K,Vt}; bias0/1/2 = bq/bk/bv.
// DBUF 1 = double-buffered cross-iter prefetch (lb 256,2 -- 64KB LDS).
template <int OUTMODE, int DBUF>
__global__ __launch_bounds__(256, DBUF ? 2 : 4)
void gemm_bt(const bf16* __restrict__ A, const bf16* __restrict__ Bm,
             const float* __restrict__ bias0, const float* __restrict__ bias1,
             const float* __restrict__ bias2, void* __restrict__ C,
             int K, int N, float alpha, long zA, long zB, long zC)
{
    __shared__ alignas(16) bf16 As[DBUF + 1][BM1 * BK1];
    __shared__ alignas(16) bf16 Bs[DBUF + 1][BN1 * BK1];

    const int tid  = threadIdx.x;
    const int lane = tid & 63;
    const int wid  = tid >> 6;
    const int wr   = (wid >> 1) * 64;   // wave row offset in tile
    const int wc   = (wid & 1) * 64;    // wave col offset in tile
    const int quad = lane >> 4;
    const int l16  = lane & 15;

    const int m0 = blockIdx.y * BM1;
    const int n0 = blockIdx.x * BN1;
    const int z  = blockIdx.z;

    const bf16* Ab = A + (size_t)z * zA + (size_t)m0 * K;
    const bf16* Bb = Bm + (size_t)z * zB + (size_t)n0 * K;

    f32x4 acc[4][4] = {};

    if (DBUF) {
        stage_tile(Ab, K, As[0], tid);
        stage_tile(Bb, K, Bs[0], tid);
    }

    const int niter = K / BK1;
    for (int it = 0; it < niter; ++it) {
        int cur;
        if (DBUF) {
            cur = it & 1;
            __syncthreads();   // buf[cur] staged; prior compute reads done
            if (it + 1 < niter) {
                stage_tile(Ab + (it + 1) * BK1, K, As[cur ^ 1], tid);
                stage_tile(Bb + (it + 1) * BK1, K, Bs[cur ^ 1], tid);
            }
        } else {
            cur = 0;
            __syncthreads();
            stage_tile(Ab + it * BK1, K, As[0], tid);
            stage_tile(Bb + it * BK1, K, Bs[0], tid);
            __syncthreads();
        }
#pragma unroll
        for (int h = 0; h < 2; ++h) {
            bf16x8 af[4], bfr[4];
#pragma unroll
            for (int i = 0; i < 4; ++i)
                af[i]  = read_frag(As[cur], wr + i * 16 + l16, h * 4 + quad);
#pragma unroll
            for (int j = 0; j < 4; ++j)
                bfr[j] = read_frag(Bs[cur], wc + j * 16 + l16, h * 4 + quad);

#pragma unroll
            for (int i = 0; i < 4; ++i)
#pragma unroll
                for (int j = 0; j < 4; ++j)
                    acc[i][j] = __builtin_amdgcn_mfma_f32_16x16x32_bf16(
                        af[i], bfr[j], acc[i][j], 0, 0, 0);
        }
    }

    // Epilogue. C/D layout (verified m89): col = lane&15, row = quad*4 + reg.
#pragma unroll
    for (int j = 0; j < 4; ++j) {
        const int col3 = n0 + wc + j * 16 + l16;
#pragma unroll
        for (int i = 0; i < 4; ++i) {
            const int rbase = m0 + wr + i * 16 + quad * 4;
            const int mat = col3 >> 10;           // 0=Q 1=K 2=V (uniform/blk)
            const int col = col3 & 1023;
            const float* bp = (mat == 0) ? bias0 : (mat == 1) ? bias1 : bias2;
            const float bj = bp[col];
            if (mat < 2) {
                bf16* Cb = (bf16*)C + (size_t)mat * (8u << 20);
#pragma unroll
                for (int r = 0; r < 4; ++r)
                    Cb[(size_t)(rbase + r) * 1024 + col] =
                        (bf16)(acc[i][j][r] + bj);
            } else {
                // Vt[b][col][s] = V[b*2048+s][col]; quad rows are 4
                // consecutive s -> one 8B same-type vector store.
                bf16* Cb = (bf16*)C + (size_t)(16u << 20);
                const int b = rbase >> 11;
                const int s = rbase & 2047;
                bf16x4 tmp;
#pragma unroll
                for (int r = 0; r < 4; ++r) tmp[r] = (bf16)(acc[i][j][r] + bj);
                *(bf16x4*)(Cb + (((size_t)((b << 10) + col)) << 11) + s) = tmp;
            }
        }
    }
}

// --------------------------------- scores/PV: 256² drift-schedule gemm -----
// OUTMODE: 2 = f16 out, scaled by alpha (scores)
//          3 = f32 out (final O -> d_out)
// NW_N: waves along N. 4 -> BN=256 (wave grid 2Mx4N, acc[8][4]);
//                      2 -> BN=128 (wave grid 4Mx2N, acc[4][4], A 3-buf).
template <int OUTMODE, int NW_N>
__global__ __launch_bounds__(512, 2)
void gemm256(const bf16* __restrict__ A, const bf16* __restrict__ Bm,
             void* __restrict__ C,
             int K, int N, float alpha, long zA, long zB, long zC)
{
    constexpr int MI = 2 * NW_N;          // A-frags per wave (8 or 4)
    extern __shared__ __align__(16) char smem[];
    auto lds3 = (__attribute__((address_space(3))) char*)smem;

    const int tid  = threadIdx.x;
    const int lane = tid & 63;
    const int wid  = tid >> 6;
    const int quad = lane >> 4;
    const int l16  = lane & 15;
    const int wc   = (wid % NW_N) * 64;         // wave col offset in tile
    const int wr   = (wid / NW_N) * (MI * 16);  // wave row offset in tile

    // T1: bijective XCD swizzle (all our grids have nwg % 8 == 0).
    const unsigned gx = gridDim.x, gy = gridDim.y;
    unsigned flat = blockIdx.x + gx * (blockIdx.y + gy * blockIdx.z);
    const unsigned chunk = (gx * gy * gridDim.z) >> 3;
    flat = (flat & 7u) * chunk + (flat >> 3);
    const int bx = flat % gx;
    const unsigned r2 = flat / gx;
    const int by = r2 % gy;
    const int z  = r2 / gy;

    const int m0 = by * 256;
    const int n0 = bx * (NW_N * 64);

    const bf16* Ab = A + (size_t)z * zA + (size_t)m0 * K;
    const bf16* Bb = Bm + (size_t)z * zB + (size_t)n0 * K;

    // DMA: dest linear (slot s = issue*512 + tid); source inverse-permuted so
    // slot (r, p) receives global chunk p ^ (r&7).
    const int sr  = tid >> 3;                    // row 0..63 (issue 0)
    const int sc  = (tid & 7) ^ (sr & 7);        // source chunk for this slot
    const size_t soff = (size_t)sr * K + (size_t)sc * 8;
    const long  hstep = 64L * K;                 // issue-1 covers rows +64
    const long  h1off = 128L * K;                // half-1 global row offset
    const unsigned dmabase = (unsigned)(wid * 1024);

#define STAGE(g, ldsoff)                                                       \
    do {                                                                       \
        __builtin_amdgcn_global_load_lds(                                      \
            (const __attribute__((address_space(1))) void*)((g) + soff),       \
            (__attribute__((address_space(3))) void*)(lds3 + (ldsoff) + dmabase), \
            16, 0, 0);                                                         \
        __builtin_amdgcn_global_load_lds(                                      \
            (const __attribute__((address_space(1))) void*)((g) + soff + hstep), \
            (__attribute__((address_space(3))) void*)(lds3 + (ldsoff) + 8192 + dmabase), \
            16, 0, 0);                                                         \
    } while (0)

    // Fragment read bases. frag (i,kk): byte = base + i*2048 + slot*16,
    // slot = (kk*4+quad) ^ (l16&7); kk=1 slot = kk=0 slot ^ 4 -> byte ^ 64.
    const char* pa = (const char*)smem + (wr + l16) * 128;
    const int x0 = (quad ^ (l16 & 7)) * 16;

    const int NT = K / 64;
    f32x4 acc[MI][4] = {};

    if constexpr (NW_N == 4) {
        // LDS: A dbuf @0/32768 ; B dbuf @65536/98304.
        const char* pb = (const char*)smem + 65536 + (wc + l16) * 128;
        bf16x8 af[4][2], b01[2][2], b23[2][2];

        // prologue: A0, B0, A1 (12 loads); vmcnt(4) -> A0+B0 landed.
        STAGE(Ab, 0u);           STAGE(Ab + h1off, 16384u);
        STAGE(Bb, 65536u);       STAGE(Bb + h1off, 65536u + 16384u);
        STAGE(Ab + 64, 32768u);  STAGE(Ab + 64 + h1off, 32768u + 16384u);
        asm volatile("s_waitcnt vmcnt(4)\n\ts_barrier" ::: "memory");

        for (int t = 0; t < NT; ++t) {
            const unsigned d  = (unsigned)(t & 1) * 32768u;
            const unsigned dn = 32768u - d;
            const char* paT = pa + d;
            const char* pbT = pb + d;

            // P0: af0-3 + b01 ; stage B-h0(t+1)
#pragma unroll
            for (int i = 0; i < 4; ++i) {
                af[i][0] = *(const bf16x8*)(paT + i * 2048 + x0);
                af[i][1] = *(const bf16x8*)(paT + i * 2048 + (x0 ^ 64));
            }
#pragma unroll
            for (int j = 0; j < 2; ++j) {
                b01[j][0] = *(const bf16x8*)(pbT + j * 2048 + x0);
                b01[j][1] = *(const bf16x8*)(pbT + j * 2048 + (x0 ^ 64));
            }
            if (t + 1 < NT) STAGE(Bb + (t + 1) * 64, 65536u + dn);
            __builtin_amdgcn_s_setprio(1);
#pragma unroll
            for (int i = 0; i < 4; ++i)
#pragma unroll
                for (int j = 0; j < 2; ++j) {
                    acc[i][j] = __builtin_amdgcn_mfma_f32_16x16x32_bf16(
                        af[i][0], b01[j][0], acc[i][j], 0, 0, 0);
                    acc[i][j] = __builtin_amdgcn_mfma_f32_16x16x32_bf16(
                        af[i][1], b01[j][1], acc[i][j], 0, 0, 0);
                }
            __builtin_amdgcn_s_setprio(0);

            // P1: b23 ; stage B-h1(t+1)
#pragma unroll
            for (int j = 0; j < 2; ++j) {
                b23[j][0] = *(const bf16x8*)(pbT + (2 + j) * 2048 + x0);
                b23[j][1] = *(const bf16x8*)(pbT + (2 + j) * 2048 + (x0 ^ 64));
            }
            if (t + 1 < NT) STAGE(Bb + (t + 1) * 64 + h1off, 65536u + dn + 16384u);
            __builtin_amdgcn_s_setprio(1);
#pragma unroll
            for (int i = 0; i < 4; ++i)
#pragma unroll
                for (int j = 0; j < 2; ++j) {
                    acc[i][2 + j] = __builtin_amdgcn_mfma_f32_16x16x32_bf16(
                        af[i][0], b23[j][0], acc[i][2 + j], 0, 0, 0);
                    acc[i][2 + j] = __builtin_amdgcn_mfma_f32_16x16x32_bf16(
                        af[i][1], b23[j][1], acc[i][2 + j], 0, 0, 0);
                }
            __builtin_amdgcn_s_setprio(0);

            // P2: af4-7
#pragma unroll
            for (int i = 0; i < 4; ++i) {
                af[i][0] = *(const bf16x8*)(paT + (4 + i) * 2048 + x0);
                af[i][1] = *(const bf16x8*)(paT + (4 + i) * 2048 + (x0 ^ 64));
            }
            __builtin_amdgcn_s_setprio(1);
#pragma unroll
            for (int i = 0; i < 4; ++i)
#pragma unroll
                for (int j = 0; j < 2; ++j) {
                    acc[4 + i][2 + j] = __builtin_amdgcn_mfma_f32_16x16x32_bf16(
                        af[i][0], b23[j][0], acc[4 + i][2 + j], 0, 0, 0);
                    acc[4 + i][2 + j] = __builtin_amdgcn_mfma_f32_16x16x32_bf16(
                        af[i][1], b23[j][1], acc[4 + i][2 + j], 0, 0, 0);
                }
            __builtin_amdgcn_s_setprio(0);

            // mid barrier: A[d] fully consumed by every wave.
            asm volatile("s_barrier" ::: "memory");

            // P3: b01 re-read ; stage A(t+2) -> A[d]
#pragma unroll
            for (int j = 0; j < 2; ++j) {
                b01[j][0] = *(const bf16x8*)(pbT + j * 2048 + x0);
                b01[j][1] = *(const bf16x8*)(pbT + j * 2048 + (x0 ^ 64));
            }
            if (t + 2 < NT) {
                STAGE(Ab + (t + 2) * 64, d);
                STAGE(Ab + (t + 2) * 64 + h1off, d + 16384u);
            }
            __builtin_amdgcn_s_setprio(1);
#pragma unroll
            for (int i = 0; i < 4; ++i)
#pragma unroll
                for (int j = 0; j < 2; ++j) {
                    acc[4 + i][j] = __builtin_amdgcn_mfma_f32_16x16x32_bf16(
                        af[i][0], b01[j][0], acc[4 + i][j], 0, 0, 0);
                    acc[4 + i][j] = __builtin_amdgcn_mfma_f32_16x16x32_bf16(
                        af[i][1], b01[j][1], acc[4 + i][j], 0, 0, 0);
                }
            __builtin_amdgcn_s_setprio(0);

            // boundary: counted landing guarantee fused with the barrier.
            if (t + 2 < NT)
                asm volatile("s_waitcnt vmcnt(4)\n\ts_barrier" ::: "memory");
            else if (t + 1 < NT)
                asm volatile("s_waitcnt vmcnt(0)\n\ts_barrier" ::: "memory");
        }
    } else {
        // NW_N == 2: A 3-buf @0/32768/65536 ; B dbuf @98304/114688.
        bf16x8 af[2][2], bfr[4][2];

        // prologue: A0 (4), B0 (2), A1 (4); vmcnt(4) -> A0+B0 landed.
        STAGE(Ab, 0u);           STAGE(Ab + h1off, 16384u);
        STAGE(Bb, 98304u);
        STAGE(Ab + 64, 32768u);  STAGE(Ab + 64 + h1off, 32768u + 16384u);
        asm volatile("s_waitcnt vmcnt(4)\n\ts_barrier" ::: "memory");

        for (int t = 0; t < NT; ++t) {
            const char* paT = pa + (unsigned)(t % 3) * 32768u;
            const char* pbT = (const char*)smem + 98304u +
                              (unsigned)(t & 1) * 16384u + (wc + l16) * 128;

            // P0: af0-1 + all bf ; stage B(t+1)
#pragma unroll
            for (int i = 0; i < 2; ++i) {
                af[i][0] = *(const bf16x8*)(paT + i * 2048 + x0);
                af[i][1] = *(const bf16x8*)(paT + i * 2048 + (x0 ^ 64));
            }
#pragma unroll
            for (int j = 0; j < 4; ++j) {
                bfr[j][0] = *(const bf16x8*)(pbT + j * 2048 + x0);
                bfr[j][1] = *(const bf16x8*)(pbT + j * 2048 + (x0 ^ 64));
            }
            if (t + 1 < NT)
                STAGE(Bb + (t + 1) * 64, 98304u + (unsigned)((t + 1) & 1) * 16384u);
            __builtin_amdgcn_s_setprio(1);
#pragma unroll
            for (int i = 0; i < 2; ++i)
#pragma unroll
                for (int j = 0; j < 4; ++j) {
                    acc[i][j] = __builtin_amdgcn_mfma_f32_16x16x32_bf16(
                        af[i][0], bfr[j][0], acc[i][j], 0, 0, 0);
                    acc[i][j] = __builtin_amdgcn_mfma_f32_16x16x32_bf16(
                        af[i][1], bfr[j][1], acc[i][j], 0, 0, 0);
                }
            __builtin_amdgcn_s_setprio(0);

            // P1: af2-3 ; stage A(t+2) -> A[(t+2)%3] (untouched by t, t+1)
#pragma unroll
            for (int i = 0; i < 2; ++i) {
                af[i][0] = *(const bf16x8*)(paT + (2 + i) * 2048 + x0);
                af[i][1] = *(const bf16x8*)(paT + (2 + i) * 2048 + (x0 ^ 64));
            }
            if (t + 2 < NT) {
                const unsigned da = (unsigned)((t + 2) % 3) * 32768u;
                STAGE(Ab + (t + 2) * 64, da);
                STAGE(Ab + (t + 2) * 64 + h1off, da + 16384u);
            }
            __builtin_amdgcn_s_setprio(1);
#pragma unroll
            for (int i = 0; i < 2; ++i)
#pragma unroll
                for (int j = 0; j < 4; ++j) {
                    acc[2 + i][j] = __builtin_amdgcn_mfma_f32_16x16x32_bf16(
                        af[i][0], bfr[j][0], acc[2 + i][j], 0, 0, 0);
                    acc[2 + i][j] = __builtin_amdgcn_mfma_f32_16x16x32_bf16(
                        af[i][1], bfr[j][1], acc[2 + i][j], 0, 0, 0);
                }
            __builtin_amdgcn_s_setprio(0);

            if (t + 2 < NT)
                asm volatile("s_waitcnt vmcnt(4)\n\ts_barrier" ::: "memory");
            else if (t + 1 < NT)
                asm volatile("s_waitcnt vmcnt(0)\n\ts_barrier" ::: "memory");
        }
    }
#undef STAGE

    // Epilogue. C/D layout (verified m89): col = lane&15, row = quad*4 + reg.
#pragma unroll
    for (int j = 0; j < 4; ++j) {
        const int col3 = n0 + wc + j * 16 + l16;
#pragma unroll
        for (int i = 0; i < MI; ++i) {
            const int rbase = m0 + wr + i * 16 + quad * 4;
            if (OUTMODE == 2) {
                f16* Cf = (f16*)C + (size_t)z * zC;
#pragma unroll
                for (int r = 0; r < 4; ++r)
                    Cf[(size_t)(rbase + r) * N + col3] = (f16)(acc[i][j][r] * alpha);
            } else { // OUTMODE == 3
                float* Cf = (float*)C + (size_t)z * zC;
#pragma unroll
                for (int r = 0; r < 4; ++r)
                    Cf[(size_t)(rbase + r) * N + col3] = acc[i][j][r];
            }
        }
    }
}

// ------------------------------------------------------------- softmax -----
__device__ __forceinline__ float wred_max(float v)
{
#pragma unroll
    for (int o = 32; o > 0; o >>= 1) v = fmaxf(v, __shfl_xor(v, o, 64));
    return v;
}
__device__ __forceinline__ float wred_sum(float v)
{
#pragma unroll
    for (int o = 32; o > 0; o >>= 1) v += __shfl_xor(v, o, 64);
    return v;
}

__global__ __launch_bounds__(256)
void softmax_rows(const f16* __restrict__ Sc, bf16* __restrict__ P)
{
    constexpr int NC = 2048;
    const size_t row = blockIdx.x;
    const f16* src = Sc + row * NC;
    bf16* dst = P + row * NC;
    const int tid = threadIdx.x;

    f16x8 in = *(const f16x8*)(src + tid * 8);
    float v[8];
    float m = -3.4e38f;
#pragma unroll
    for (int i = 0; i < 8; ++i) {
        v[i] = (float)in[i];
        m = fmaxf(m, v[i]);
    }
    m = wred_max(m);

    __shared__ float redm[4], reds[4];
    if ((tid & 63) == 0) redm[tid >> 6] = m;
    __syncthreads();
    m = fmaxf(fmaxf(redm[0], redm[1]), fmaxf(redm[2], redm[3]));

    float s = 0.f;
#pragma unroll
    for (int i = 0; i < 8; ++i) { v[i] = __expf(v[i] - m); s += v[i]; }
    s = wred_sum(s);
    if ((tid & 63) == 0) reds[tid >> 6] = s;
    __syncthreads();
    s = reds[0] + reds[1] + reds[2] + reds[3];

    const float inv = 1.f / s;
    bf16x8 o;
#pragma unroll
    for (int i = 0; i < 8; ++i) o[i] = (bf16)(v[i] * inv);
    *(bf16x8*)(dst + tid * 8) = o;
}

// ------------------------------------------------------------- launch ------
extern "C" void kernel_launch(void* const* d_in, const int* in_sizes, int n_in,
                              void* d_out, int out_size, void* d_ws, size_t ws_size,
                              hipStream_t stream)
{
    constexpr int B = 4, S = 2048, H = 1024;
    const float* x  = (const float*)d_in[0];
    const float* Wq = (const float*)d_in[1];
    const float* bq = (const float*)d_in[2];
    const float* Wk = (const float*)d_in[3];
    const float* bk = (const float*)d_in[4];
    const float* Wv = (const float*)d_in[5];
    const float* bv = (const float*)d_in[6];
    float* out = (float*)d_out;

    char* ws = (char*)d_ws;
    bf16* xb   = (bf16*)ws;                         // 16 MB
    bf16* Wqkv = (bf16*)(ws + (size_t)(16 << 20));  //  6 MB (Wq|Wk|Wv bf16)
    bf16* Q    = (bf16*)(ws + (size_t)(22 << 20));  // 16 MB
    bf16* Kp   = (bf16*)(ws + (size_t)(38 << 20));  // 16 MB
    bf16* Vt   = (bf16*)(ws + (size_t)(54 << 20));  // 16 MB
    f16*  Sc   = (f16*) (ws + (size_t)(70 << 20));  // 32 MB (fp16 scores)
    bf16* P    = (bf16*)(ws + (size_t)(22 << 20));  // 32 MB, overlays Q|Kp

    static bool attr_done = false;
    if (!attr_done) {
        attr_done = true;
        (void)hipFuncSetAttribute(reinterpret_cast<const void*>(gemm256<2, 4>),
                                  hipFuncAttributeMaxDynamicSharedMemorySize,
                                  LDS_TOTAL);
        (void)hipFuncSetAttribute(reinterpret_cast<const void*>(gemm256<3, 2>),
                                  hipFuncAttributeMaxDynamicSharedMemorySize,
                                  LDS_TOTAL);
    }

    dim3 blk(256, 1, 1);
    dim3 blk512(512, 1, 1);

    // fp32 -> bf16 conversions, one dispatch (x -> xb, Wq|Wk|Wv -> Wqkv)
    cvt_all<<<dim3((XQ + 3 * WQ) / 256), blk, 0, stream>>>(
        x, Wq, Wk, Wv, xb, Wqkv);

    // Fused QKV projection: M = 8192, N = 3072, K = 1024 -> Q, Kp, Vt
    // (R0-proven 128² dbuf kernel, 71.6µs measured)
    gemm_bt<4, 1><<<dim3(3 * H / BN1, (B * S) / BM1, 1), blk, 0, stream>>>(
        xb, Wqkv, bq, bk, bv, Q, H, 3 * H, 1.0f, 0, 0, 0);

    // Scores: per batch, Sc = Q·Kᵀ / 32, fp16  (grid 8x8x4 = 256 = 1/CU)
    gemm256<2, 4><<<dim3(S / 256, S / 256, B), blk512, LDS_TOTAL, stream>>>(
        Q, Kp, Sc, H, S, 0.03125f,
        (long)S * H, (long)S * H, (long)S * S);

    // Row softmax: 8192 rows of 2048
    softmax_rows<<<dim3(B * S), blk, 0, stream>>>(Sc, P);

    // O = P·Vtᵀ -> out (fp32)  (BN=128: grid 8x8x4 = 256, full GPU)
    gemm256<3, 2><<<dim3(H / 128, S / 256, B), blk512, LDS_TOTAL, stream>>>(
        P, Vt, out, S, H, 1.0f,
        (long)S * S, (long)H * S, (long)S * H);
}